// Round 1
// baseline (221.144 us; speedup 1.0000x reference)
//
#include <hip/hip_runtime.h>

#define C_IN   672
#define C_OUT  128
#define HW     49
#define XELEMS (C_IN*HW)      // 32928
#define BK     96             // K-chunk (3 MFMA k-steps)
#define NCH    7              // 672/96
#define RS     104            // LDS row stride in bf16 elems (16B-aligned rows, 2-way read alias = free)
#define NROWS  64             // padded N (s) dimension

typedef short  short8 __attribute__((ext_vector_type(8)));
typedef float  f4     __attribute__((ext_vector_type(4)));

__device__ __forceinline__ unsigned short f2bf(float f) {
    // round-to-nearest-even fp32 -> bf16 (values here are finite)
    unsigned u = __float_as_uint(f);
    u += 0x7fffu + ((u >> 16) & 1u);
    return (unsigned short)(u >> 16);
}

__global__ __launch_bounds__(256) void prep_kernel(
        const float* __restrict__ gamma,
        const float* __restrict__ beta,
        const float* __restrict__ rmean,
        const float* __restrict__ rvar,
        const float* __restrict__ W,
        unsigned short* __restrict__ Wbf,
        float* __restrict__ scale,
        float* __restrict__ shift) {
    int i = blockIdx.x * 256 + threadIdx.x;
    if (i < C_IN) {
        float inv = rsqrtf(rvar[i] + 1e-5f);
        float sc  = gamma[i] * inv;
        scale[i] = sc;
        shift[i] = beta[i] - rmean[i] * sc;
    }
    if (i < C_OUT * C_IN) Wbf[i] = f2bf(W[i]);
}

// One block per batch element b: out_b(128x49) = W(128x672) @ h_b(672x49)
// h_b = relu(x_b * scale + shift), staged transposed (hT[s][c]) in LDS as bf16.
__global__ __launch_bounds__(256) void gemm_kernel(
        const float* __restrict__ x,
        const unsigned short* __restrict__ Wbf,
        const float* __restrict__ scale,
        const float* __restrict__ shift,
        float* __restrict__ out) {
    __shared__ float s_scale[C_IN];
    __shared__ float s_shift[C_IN];
    __shared__ unsigned short hT[NROWS * RS];   // 13312 B

    const int tid  = threadIdx.x;
    const int b    = blockIdx.x;
    const int wv   = tid >> 6;        // wave 0..3 -> m-strip of 32 rows
    const int lane = tid & 63;
    const int quad = lane >> 4;
    const int l16  = lane & 15;

    const float* xb = x + (size_t)b * XELEMS;

    for (int i = tid; i < C_IN; i += 256) {
        s_scale[i] = scale[i];
        s_shift[i] = shift[i];
    }

    f4 acc[2][4];
    #pragma unroll
    for (int mt = 0; mt < 2; ++mt)
        #pragma unroll
        for (int nt = 0; nt < 4; ++nt)
            acc[mt][nt] = (f4){0.f, 0.f, 0.f, 0.f};

    for (int ch = 0; ch < NCH; ++ch) {
        __syncthreads();   // hT safe to overwrite (also covers scale/shift staging on ch==0)

        // ---- stage chunk: 96 channels x 49 spatial = 4704 floats = 1176 float4, coalesced
        const f4* xc = (const f4*)(xb + ch * (BK * HW));
        for (int p = tid; p < (BK * HW / 4); p += 256) {
            f4 v = xc[p];
            int e  = p * 4;
            int cc = e / HW;          // compiler magic-div by 49
            int s  = e - cc * HW;
            #pragma unroll
            for (int j = 0; j < 4; ++j) {
                float val = fmaxf(v[j] * s_scale[ch * BK + cc] + s_shift[ch * BK + cc], 0.f);
                hT[s * RS + cc] = f2bf(val);
                if (++s == HW) { s = 0; ++cc; }
            }
        }
        __syncthreads();

        // ---- 3 MFMA k-steps over this chunk
        #pragma unroll
        for (int ks = 0; ks < 3; ++ks) {
            const int kloc = ks * 32 + quad * 8;
            short8 av[2];
            #pragma unroll
            for (int mt = 0; mt < 2; ++mt) {
                int row = wv * 32 + mt * 16 + l16;   // A[m=l16-ish][k] from L2-resident bf16 W
                av[mt] = *(const short8*)(Wbf + row * C_IN + ch * BK + kloc);
            }
            short8 bv[4];
            #pragma unroll
            for (int nt = 0; nt < 4; ++nt) {
                int srow = nt * 16 + l16;            // B[k][n=l16] via ds_read_b128
                bv[nt] = *(const short8*)(hT + srow * RS + kloc);
            }
            #pragma unroll
            for (int mt = 0; mt < 2; ++mt)
                #pragma unroll
                for (int nt = 0; nt < 4; ++nt)
                    acc[mt][nt] = __builtin_amdgcn_mfma_f32_16x16x32_bf16(
                        av[mt], bv[nt], acc[mt][nt], 0, 0, 0);
        }
    }

    // ---- epilogue: C/D layout col=lane&15, row=quad*4+reg (m89-verified); mask s>=49
    float* outb = out + (size_t)b * (C_OUT * HW);
    #pragma unroll
    for (int mt = 0; mt < 2; ++mt) {
        #pragma unroll
        for (int nt = 0; nt < 4; ++nt) {
            int scol = nt * 16 + l16;
            if (scol < HW) {
                #pragma unroll
                for (int i = 0; i < 4; ++i) {
                    int o = wv * 32 + mt * 16 + quad * 4 + i;
                    outb[o * HW + scol] = acc[mt][nt][i];
                }
            }
        }
    }
}

extern "C" void kernel_launch(void* const* d_in, const int* in_sizes, int n_in,
                              void* d_out, int out_size, void* d_ws, size_t ws_size,
                              hipStream_t stream) {
    const float* x     = (const float*)d_in[0];
    const float* gamma = (const float*)d_in[1];
    const float* beta  = (const float*)d_in[2];
    const float* rmean = (const float*)d_in[3];
    const float* rvar  = (const float*)d_in[4];
    const float* W     = (const float*)d_in[5];
    float* out = (float*)d_out;

    // ws layout: [bf16 W: 86016*2 B][scale: 672 f32][shift: 672 f32]  (~173 KB)
    unsigned short* Wbf = (unsigned short*)d_ws;
    float* scale = (float*)((char*)d_ws + (size_t)C_OUT * C_IN * 2);
    float* shift = scale + C_IN;

    prep_kernel<<<(C_OUT * C_IN + 255) / 256, 256, 0, stream>>>(
        gamma, beta, rmean, rvar, W, Wbf, scale, shift);
    gemm_kernel<<<1024, 256, 0, stream>>>(x, Wbf, scale, shift, out);
}